// Round 11
// baseline (3103.162 us; speedup 1.0000x reference)
//
#include <hip/hip_runtime.h>
#include <hip/hip_fp16.h>
#include <math.h>

#define Tt 64
#define Bb 16
#define Nn 256
#define Ww 64
#define Rr 4
#define INd 64
#define OUTd 64
#define IFS 471
#define EPSf 1e-6f

// packed half2 weight layout offsets (in half2 units), pairs along K
#define W1OFF   0        // 160*256
#define W2OFF   40960    // 128*256
#define WIFOFF  73728    // 128*471
#define WOUTOFF 134016   // 128*64
#define WMEMOFF 142208   // 128*64
#define WTOT    150400

// link: 256 rows x 129 dwords (258 halfs; 256 used + 2 pad)
#define LROW    129
#define LINKB   (256 * LROW * 4)     // 132096 B
#define SCRB    16384                // bwd partials: 8kc*128p*8 halfs = 16 KB
#define FIXF    3072
#define SMEM_MAIN (LINKB + SCRB + FIXF * 4)   // 160768 <= 163840
#define SMEM_FB   (SCRB + FIXF * 4)

typedef _Float16 h2v __attribute__((ext_vector_type(2)));
__device__ __forceinline__ float fdot2(__half2 a, __half2 b, float c) {
    return __builtin_amdgcn_fdot2(*(h2v*)&a, *(h2v*)&b, c, false);
}
__device__ __forceinline__ __half2 pkh(float a, float b) {
    auto r = __builtin_amdgcn_cvt_pkrtz(a, b);   // __fp16 ext_vector(2)
    return *(__half2*)&r;
}

__device__ __forceinline__ float sigm(float x) { return 1.f / (1.f + expf(-x)); }
__device__ __forceinline__ float oneplus_(float x) {
    return 1.f + fmaxf(x, 0.f) + log1pf(expf(-fabsf(x)));
}
__device__ __forceinline__ float wsum(float v) {
#pragma unroll
    for (int o = 32; o; o >>= 1) v += __shfl_xor(v, o, 64);
    return v;
}
__device__ __forceinline__ float wmaxr(float v) {
#pragma unroll
    for (int o = 32; o; o >>= 1) v = fmaxf(v, __shfl_xor(v, o, 64));
    return v;
}

// shared GEMV-partial body (one icache copy)
__device__ __attribute__((noinline)) float gemv_part(
    const __half2* __restrict__ wP, int stride, int iters,
    const __half2* __restrict__ vin)
{
    float a[8] = {0.f,0.f,0.f,0.f,0.f,0.f,0.f,0.f};
#pragma unroll 1
    for (int j0 = 0; j0 < iters; j0 += 8) {
        __half2 hh[8], vv[8];
#pragma unroll
        for (int u = 0; u < 8; ++u) hh[u] = wP[(j0 + u) * stride];
#pragma unroll
        for (int u = 0; u < 8; ++u) vv[u] = vin[j0 + u];
#pragma unroll
        for (int u = 0; u < 8; ++u) a[u] = fdot2(hh[u], vv[u], a[u]);
    }
    return ((a[0]+a[1])+(a[2]+a[3])) + ((a[4]+a[5])+(a[6]+a[7]));
}

// ---- converter: fp32 weights -> packed half2 (pairs along K) ----
__global__ void convert_weights(const float* __restrict__ W1, const float* __restrict__ W2,
                                const float* __restrict__ Wif, const float* __restrict__ Wout,
                                const float* __restrict__ Wmem, __half2* __restrict__ wp) {
    int i = blockIdx.x * blockDim.x + threadIdx.x;
    if (i >= WTOT) return;
    float a, b;
    if (i < W2OFF)        { int r = i;           int k2 = r >> 8, n = r & 255; a = W1[(2*k2)*256+n];  b = W1[(2*k2+1)*256+n]; }
    else if (i < WIFOFF)  { int t = i - W2OFF;   int k2 = t >> 8, n = t & 255; a = W2[(2*k2)*256+n];  b = W2[(2*k2+1)*256+n]; }
    else if (i < WOUTOFF) { int t = i - WIFOFF;  int k2 = t / IFS, o = t - IFS*k2; a = Wif[(2*k2)*IFS+o]; b = Wif[(2*k2+1)*IFS+o]; }
    else if (i < WMEMOFF) { int t = i - WOUTOFF; int k2 = t >> 6, n = t & 63;  a = Wout[(2*k2)*64+n]; b = Wout[(2*k2+1)*64+n]; }
    else                  { int t = i - WMEMOFF; int k2 = t >> 6, n = t & 63;  a = Wmem[(2*k2)*64+n]; b = Wmem[(2*k2+1)*64+n]; }
    wp[i] = __floats2half2_rn(a, b);
}

template <bool LLINK>
__global__ __launch_bounds__(1024) void dnc_kernel(
    const float* __restrict__ x, const float* __restrict__ b1,
    const float* __restrict__ b2, const float* __restrict__ bif,
    const __half2* __restrict__ wp,
    __half* __restrict__ memg,      // per batch 64*256 halves, [w][n]
    __half* __restrict__ memTg,     // per batch 256*64 halves, [n][w] (transposed)
    __half2* __restrict__ linkg,    // fallback link
    float* __restrict__ out)
{
    extern __shared__ __align__(16) char smem[];
    const int b = blockIdx.x;
    const int tid = threadIdx.x;
    const int lane = tid & 63;
    const int wv = tid >> 6;

    __half2* l2p = (__half2*)smem;
    __half2* gl2 = linkg + (size_t)b * (256 * LROW);
    float* scr   = (float*)(smem + (LLINK ? LINKB : 0));
    __half* scrh = (__half*)scr;
    float* fx    = (float*)((char*)scr + SCRB);

    // NOTE: half2 = 4 B = 1 float slot. Offsets audited (R10 bug: halved sizes).
    __half2* s_ctrlh = (__half2*)(fx + 0);        // 160 h2: [0,32) x, [32,160) rvec
    __half2* s_hh    = (__half2*)(fx + 160);      // 128 h2
    __half2* s_nnh   = (__half2*)(fx + 288);      // 128 h2
    __half2* s_rwh   = (__half2*)(fx + 416);      // 516 h2: [r][129 n-pairs] (pad)
    // ZONE fx+932..1956 (dead after P6): s_z+wc partials; reused as fwdh in P8/P9
    float* s_z     = fx + 932;    // 472
    float* s_wcdot = fx + 1404;   // 256
    float* s_wcss  = fx + 1660;   // 256
    __half* fwdh   = (__half*)(fx + 932);  // 2048 halfs [q2][r][n] = 1024 floats
    float* s_usage = fx + 1956;   // 256
    float* s_ww    = fx + 2212;   // 256
    float* s_prec  = fx + 2468;   // 256
    float* s_knorm = fx + 2724;   // 4
    float* s_rstr  = fx + 2728;   // 4
    float* s_rmode = fx + 2732;   // 12
    float* s_sc    = fx + 2744;   // 4
    float* s_red   = fx + 2748;   // 32
    __half2* s_wkh = (__half2*)(fx + 2780);  // 32 h2 (wkey w-pairs)
    __half2* s_rkh = (__half2*)(fx + 2812);  // 128 h2 [r][32 w-pairs]
    float* s_er    = fx + 2940;   // 64
    float* s_wv    = fx + 3004;   // 64  -> FIXF 3072
    float* s_srt   = scr + 1024;  // 256 (mega window only)
    float* s_cp    = scr + 1280;  // 256 (mega window only)

    __half*  memh   = memg  + (size_t)b * (Ww * Nn);
    __half2* memh2  = (__half2*)memh;
    __half*  memT_h = memTg + (size_t)b * (Ww * Nn);
    __half2* memT2  = (__half2*)memT_h;

    auto lread = [&](int idx) -> __half2 {
        if constexpr (LLINK) return l2p[idx]; else return gl2[idx];
    };
    auto lwrite = [&](int idx, __half2 v) {
        if constexpr (LLINK) l2p[idx] = v; else gl2[idx] = v;
    };

    // ---- init (ws/LDS poisoned before every launch) ----
    {
        __half2 z2 = pkh(0.f, 0.f);
#pragma unroll 1
        for (int i = tid; i < 256 * LROW; i += 1024) lwrite(i, z2);
        __half2 e2 = __floats2half2_rn(EPSf, EPSf);
#pragma unroll 1
        for (int j = 0; j < 8; ++j) { memh2[tid + j * 1024] = e2; memT2[tid + j * 1024] = e2; }
        if (tid < 516) s_rwh[tid] = z2;
        if (tid < 32) {
            float2 xv = *(const float2*)&x[b * INd + 2 * tid];
            s_ctrlh[tid] = pkh(xv.x, xv.y);
        } else if (tid < 160) s_ctrlh[tid] = z2;
    }
    if (tid < 256) { s_usage[tid] = 0.f; s_ww[tid] = 0.f; s_prec[tid] = 0.f; }

#pragma unroll 1
    for (int t = 0; t < Tt; ++t) {
        __syncthreads();  // B0

        // ---- P1: GEMV1 partials ----
        {
            int kc = wv >> 2, o = (wv & 3) * 64 + lane;
            scr[kc * 256 + o] = gemv_part(wp + W1OFF + kc * 40 * 256 + o, 256, 40,
                                          s_ctrlh + kc * 40);
        }
        __syncthreads();  // B1
        if (tid < 256) {
            float v = tanhf(b1[tid] + ((scr[tid] + scr[256+tid]) + (scr[512+tid] + scr[768+tid])));
            float pv = __shfl_xor(v, 1, 64);
            if ((tid & 1) == 0) s_hh[tid >> 1] = pkh(v, pv);
        }
        __syncthreads();  // B2

        // ---- P2: GEMV2 partials ----
        {
            int kc = wv >> 2, o = (wv & 3) * 64 + lane;
            scr[kc * 256 + o] = gemv_part(wp + W2OFF + kc * 32 * 256 + o, 256, 32,
                                          s_hh + kc * 32);
        }
        __syncthreads();  // B3
        if (tid < 256) {
            float v = tanhf(b2[tid] + ((scr[tid] + scr[256+tid]) + (scr[512+tid] + scr[768+tid])));
            float pv = __shfl_xor(v, 1, 64);
            if ((tid & 1) == 0) s_nnh[tid >> 1] = pkh(v, pv);
        }
        __syncthreads();  // B4

        // ---- P3: GEMV3 partials ----
        {
            int kc = wv >> 3, o = (wv & 7) * 64 + lane;
            if (o < IFS)
                scr[kc * 512 + o] = gemv_part(wp + WIFOFF + kc * 64 * IFS + o, IFS, 64,
                                              s_nnh + kc * 64);
        }
        __syncthreads();  // B5
        if (tid < IFS) s_z[tid] = bif[tid] + scr[tid] + scr[512 + tid];
        __syncthreads();  // B6

        // ---- P4: scalars + key packs + usage + er/wv + wc (memT + fdot2) ----
        if (wv < 4) {
            float vz = s_z[lane * 4 + wv];
            float s = wsum(vz * vz);
            if (lane == 0) s_knorm[wv] = sqrtf(s) + EPSf;
        } else if (wv == 4) {
            float vz = s_z[260 + lane];
            float s = wsum(vz * vz);
            if (lane == 0) s_sc[3] = sqrtf(s) + EPSf;
        } else if (wv == 5) {
            if (lane < 4) s_rstr[lane] = oneplus_(s_z[256 + lane]);
            else if (lane >= 8 && lane < 12) {
                int r = lane - 8;
                float a = s_z[459+r], bm = s_z[463+r], c = s_z[467+r];
                float mx = fmaxf(a, fmaxf(bm, c));
                float ea = expf(a-mx), eb = expf(bm-mx), ec = expf(c-mx);
                float inv = 1.f / ((ea+eb)+ec);
                s_rmode[0*4+r] = ea*inv; s_rmode[1*4+r] = eb*inv; s_rmode[2*4+r] = ec*inv;
            } else if (lane == 16) s_sc[0] = oneplus_(s_z[324]);
            else if (lane == 17) s_sc[1] = sigm(s_z[457]);
            else if (lane == 18) s_sc[2] = sigm(s_z[458]);
        } else if (wv == 6 || wv == 7) {
            int idx = (wv - 6) * 64 + lane;     // 0..127
            int r = idx >> 5, wp_ = idx & 31;
            s_rkh[r * 32 + wp_] = pkh(s_z[(2*wp_)*4 + r], s_z[(2*wp_+1)*4 + r]);
        } else if (wv >= 8 && wv < 12) {
            int n = tid - 512;
            int np = n >> 1, hi = n & 1;
            float ret = 1.f;
#pragma unroll
            for (int r = 0; r < 4; ++r) {
                float fg = sigm(s_z[453 + r]);
                __half2 rp = s_rwh[r * 129 + np];
                float rwv = hi ? __half2float(__high2half(rp)) : __half2float(__low2half(rp));
                ret *= 1.f - fg * rwv;
            }
            float u = s_usage[n], wwo = s_ww[n];
            s_usage[n] = (u + wwo - u * wwo) * ret;
            if (n < 64) { s_er[n] = sigm(s_z[325 + n]); s_wv[n] = s_z[389 + n]; }
        } else {  // waves 12-15: wc content pass on OLD memT
            int n = tid - 768;
            if (lane < 32) s_wkh[lane] = pkh(s_z[260 + 2*lane], s_z[260 + 2*lane + 1]);
            float dot = 0.f, ssv = 0.f;
#pragma unroll 1
            for (int wp0 = 0; wp0 < 32; wp0 += 8) {
                __half2 mt[8], kk[8];
#pragma unroll
                for (int u = 0; u < 8; ++u) mt[u] = memT2[n * 32 + wp0 + u];
#pragma unroll
                for (int u = 0; u < 8; ++u) kk[u] = s_wkh[wp0 + u];
#pragma unroll
                for (int u = 0; u < 8; ++u) {
                    dot = fdot2(mt[u], kk[u], dot);
                    ssv = fdot2(mt[u], mt[u], ssv);
                }
            }
            s_wcdot[n] = dot; s_wcss[n] = ssv;
        }
        __syncthreads();  // B7

        // ---- P5: rank partials ----
        {
            int q = tid >> 8, n = tid & 255;
            float un = s_usage[n];
            float cnt = 0.f;
            int j0 = q * 64;
#pragma unroll 1
            for (int j = j0; j < j0 + 64; ++j) {
                float uj = s_usage[j];
                if (uj < un || (uj == un && j < n)) cnt += 1.f;
            }
            scr[q * 256 + n] = cnt;
        }
        __syncthreads();  // B8

        // ---- P6: mega (wave 0) ----
        if (wv == 0) {
            int rk[4]; float uu[4];
#pragma unroll
            for (int i = 0; i < 4; ++i) {
                int n = lane * 4 + i;
                float c = scr[n] + scr[256+n] + scr[512+n] + scr[768+n];
                rk[i] = (int)(c + 0.5f);
                uu[i] = s_usage[n];
                s_srt[rk[i]] = uu[i];
            }
            float4 vs = ((const float4*)s_srt)[lane];
            float p1 = vs.x * vs.y, p2 = p1 * vs.z, tot = p2 * vs.w;
            float incl = tot;
#pragma unroll
            for (int off = 1; off < 64; off <<= 1) {
                float tv = __shfl_up(incl, off, 64);
                if (lane >= off) incl *= tv;
            }
            float excl = __shfl_up(incl, 1, 64);
            if (lane == 0) excl = 1.f;
            float4 o4v; o4v.x = excl; o4v.y = excl*vs.x; o4v.z = excl*p1; o4v.w = excl*p2;
            ((float4*)s_cp)[lane] = o4v;

            float sims[4], mx = -1e30f;
#pragma unroll
            for (int i = 0; i < 4; ++i) {
                int n = lane * 4 + i;
                sims[i] = s_wcdot[n] / ((sqrtf(s_wcss[n]) + EPSf) * s_sc[3]) * s_sc[0];
                mx = fmaxf(mx, sims[i]);
            }
            mx = wmaxr(mx);
            float es[4], ls = 0.f;
#pragma unroll
            for (int i = 0; i < 4; ++i) { es[i] = expf(sims[i] - mx); ls += es[i]; }
            ls = wsum(ls);
            float ag = s_sc[1], wg = s_sc[2], inv = 1.f / ls, lw = 0.f;
#pragma unroll
            for (int i = 0; i < 4; ++i) {
                int n = lane * 4 + i;
                float alloc = (1.f - uu[i]) * s_cp[rk[i]];
                float wwn = wg * (ag * alloc + (1.f - ag) * es[i] * inv);
                s_ww[n] = wwn; lw += wwn;
            }
            lw = wsum(lw);
            if (lane == 0) s_red[0] = lw;
        }
        __syncthreads();  // B9

        // ---- P7: link pass (16 waves, kc=8 x p=128, 32 k each) + mem RMW ----
        {
            int kc = tid >> 7, p = tid & 127;
            int c0 = 2 * p, c1 = c0 + 1;
            float wwc0 = s_ww[c0], wwc1 = s_ww[c1];
            float pt0 = s_prec[c0], pt1 = s_prec[c1];
            float acc[8] = {0,0,0,0,0,0,0,0};
            int kbase = kc * 32;
#pragma unroll 1
            for (int k0 = kbase; k0 < kbase + 32; k0 += 8) {
                __half2 lv[8];
#pragma unroll
                for (int u = 0; u < 8; ++u) lv[u] = lread((k0 + u) * LROW + p);
                float l0v[8], l1v[8];
#pragma unroll
                for (int u = 0; u < 8; ++u) {
                    int k = k0 + u;
                    float wk = s_ww[k];
                    float2 lf = __half22float2(lv[u]);
                    float l0 = (1.f - wk - wwc0) * lf.x + wk * pt0;
                    float l1 = (1.f - wk - wwc1) * lf.y + wk * pt1;
                    if (k == c0) l0 = 0.f;
                    if (k == c1) l1 = 0.f;
                    l0v[u] = l0; l1v[u] = l1;
                }
#pragma unroll
                for (int u = 0; u < 8; ++u)
                    lwrite((k0 + u) * LROW + p, pkh(l0v[u], l1v[u]));
                __half2 l0p[4], l1p[4];
#pragma unroll
                for (int i = 0; i < 4; ++i) {
                    l0p[i] = pkh(l0v[2*i], l0v[2*i+1]);
                    l1p[i] = pkh(l1v[2*i], l1v[2*i+1]);
                }
                int kp0 = k0 >> 1;
#pragma unroll
                for (int r = 0; r < 4; ++r) {
                    __half2 rp[4];
#pragma unroll
                    for (int i = 0; i < 4; ++i) rp[i] = s_rwh[r * 129 + kp0 + i];
#pragma unroll
                    for (int i = 0; i < 4; ++i) {
                        acc[r]     = fdot2(l0p[i], rp[i], acc[r]);
                        acc[4 + r] = fdot2(l1p[i], rp[i], acc[4 + r]);
                    }
                }
            }
            __half2* bp = (__half2*)scrh + (kc * 128 + p) * 4;
            bp[0] = pkh(acc[0], acc[1]);
            bp[1] = pkh(acc[2], acc[3]);
            bp[2] = pkh(acc[4], acc[5]);
            bp[3] = pkh(acc[6], acc[7]);
        }
        {   // mem RMW: 8 half2/thread; maintains [w][n] and transposed [n][w]
            __half2 mv[8];
#pragma unroll
            for (int u = 0; u < 8; ++u) mv[u] = memh2[tid + u * 1024];
#pragma unroll
            for (int u = 0; u < 8; ++u) {
                int i2 = tid + u * 1024;
                int w = i2 >> 7, n2 = i2 & 127;
                float er = s_er[w], wvv = s_wv[w];
                float2 mf = __half22float2(mv[u]);
                float wa = s_ww[2*n2], wb = s_ww[2*n2 + 1];
                mf.x = mf.x * (1.f - wa * er) + wa * wvv;
                mf.y = mf.y * (1.f - wb * er) + wb * wvv;
                __half2 pk = pkh(mf.x, mf.y);
                memh2[i2] = pk;
                memT_h[(2*n2) * 64 + w] = __low2half(pk);
                memT_h[(2*n2 + 1) * 64 + w] = __high2half(pk);
            }
        }
        __syncthreads();  // B10

        // ---- P8: fwd row pass (q2 halves x r-pairs x n) + prec update ----
        {
            int q2 = tid >> 9, rp2 = (tid >> 8) & 1, n8 = tid & 255;
            int r0 = 2 * rp2, r1 = r0 + 1;
            float f0 = 0.f, f1 = 0.f;
            int base = n8 * LROW + q2 * 64;
#pragma unroll 1
            for (int j0 = 0; j0 < 64; j0 += 8) {
                __half2 lv[8], rA[8], rB[8];
#pragma unroll
                for (int u = 0; u < 8; ++u) lv[u] = lread(base + j0 + u);
#pragma unroll
                for (int u = 0; u < 8; ++u) rA[u] = s_rwh[r0 * 129 + q2 * 64 + j0 + u];
#pragma unroll
                for (int u = 0; u < 8; ++u) rB[u] = s_rwh[r1 * 129 + q2 * 64 + j0 + u];
#pragma unroll
                for (int u = 0; u < 8; ++u) {
                    f0 = fdot2(lv[u], rA[u], f0);
                    f1 = fdot2(lv[u], rB[u], f1);
                }
            }
            fwdh[(q2 * 4 + r0) * 256 + n8] = __float2half(f0);
            fwdh[(q2 * 4 + r1) * 256 + n8] = __float2half(f1);
            if (tid < 256) s_prec[tid] = (1.f - s_red[0]) * s_prec[tid] + s_ww[tid];
        }
        __syncthreads();  // B11

        // ---- P9: rc sim (memT + fdot2, no-max softmax) + bwd/fwd reduce ----
        int rr = tid >> 8, n8c = tid & 255;
        float bwv = 0.f, fwv = 0.f, e_rc = 0.f;
        {
#pragma unroll
            for (int kc = 0; kc < 8; ++kc)
                bwv += __half2float(scrh[(kc * 128 + (n8c >> 1)) * 8 + (n8c & 1) * 4 + rr]);
            fwv = __half2float(fwdh[(0 * 4 + rr) * 256 + n8c])
                + __half2float(fwdh[(1 * 4 + rr) * 256 + n8c]);
            float dot = 0.f, ssv = 0.f;
#pragma unroll 1
            for (int wp0 = 0; wp0 < 32; wp0 += 8) {
                __half2 mt[8], kk[8];
#pragma unroll
                for (int u = 0; u < 8; ++u) mt[u] = memT2[n8c * 32 + wp0 + u];
#pragma unroll
                for (int u = 0; u < 8; ++u) kk[u] = s_rkh[rr * 32 + wp0 + u];
#pragma unroll
                for (int u = 0; u < 8; ++u) {
                    dot = fdot2(mt[u], kk[u], dot);
                    ssv = fdot2(mt[u], mt[u], ssv);
                }
            }
            float sim = dot / ((sqrtf(ssv) + EPSf) * s_knorm[rr]) * s_rstr[rr];
            e_rc = expf(sim);           // |sim| <= ~oneplus(z): exp safe in fp32
            float s = wsum(e_rc);
            if (lane == 0) s_red[wv] = s;
        }
        __syncthreads();  // B12
        {
            float sm = (s_red[rr*4+0] + s_red[rr*4+1]) + (s_red[rr*4+2] + s_red[rr*4+3]);
            float rc = e_rc / sm;
            float v = bwv * s_rmode[0*4+rr] + rc * s_rmode[1*4+rr] + fwv * s_rmode[2*4+rr];
            float pv = __shfl_xor(v, 1, 64);
            if ((n8c & 1) == 0) s_rwh[rr * 129 + (n8c >> 1)] = pkh(v, pv);
        }
        __syncthreads();  // B13

        // ---- P12: rvec partials (half2 + fdot2) ----
        {
            int kc = tid >> 8, o = tid & 255, w = o >> 2, r = o & 3;
            float a = 0.f;
#pragma unroll 1
            for (int j0 = 0; j0 < 32; j0 += 8) {
                __half2 mm[8], rp[8];
#pragma unroll
                for (int u = 0; u < 8; ++u) mm[u] = memh2[w * 128 + kc * 32 + j0 + u];
#pragma unroll
                for (int u = 0; u < 8; ++u) rp[u] = s_rwh[r * 129 + kc * 32 + j0 + u];
#pragma unroll
                for (int u = 0; u < 8; ++u) a = fdot2(mm[u], rp[u], a);
            }
            scr[kc * 256 + o] = a;
        }
        __syncthreads();  // B14

        // ---- P13: rvec reduce -> ctrl pairs + next-x staging ----
        if (tid < 256) {
            float v = (scr[tid] + scr[256+tid]) + (scr[512+tid] + scr[768+tid]);
            float pv = __shfl_xor(v, 1, 64);
            if ((tid & 1) == 0) s_ctrlh[32 + (tid >> 1)] = pkh(v, pv);
        } else if (tid >= 512 && tid < 544) {
            if (t + 1 < Tt) {
                int i = tid - 512;
                float2 xv = *(const float2*)&x[((t + 1) * Bb + b) * INd + 2 * i];
                s_ctrlh[i] = pkh(xv.x, xv.y);
            }
        }
        __syncthreads();  // B15

        // ---- P14: out GEMV partials ----
        {
            int c4 = wv, o4 = lane;
            const __half2* wsrc = (c4 < 8) ? (wp + WOUTOFF + (c4 * 16) * 64 + o4)
                                           : (wp + WMEMOFF + ((c4 - 8) * 16) * 64 + o4);
            const __half2* vsrc = (c4 < 8) ? (s_nnh + c4 * 16)
                                           : (s_ctrlh + 32 + (c4 - 8) * 16);
            scr[c4 * 64 + o4] = gemv_part(wsrc, 64, 16, vsrc);
        }
        __syncthreads();  // B16
        if (tid < 64) {
            float s = 0.f;
#pragma unroll
            for (int g = 0; g < 16; ++g) s += scr[g * 64 + tid];
            out[(t * Bb + b) * OUTd + tid] = s;
        }
        // loop-top barrier covers remaining hazards
    }
}

extern "C" void kernel_launch(void* const* d_in, const int* in_sizes, int n_in,
                              void* d_out, int out_size, void* d_ws, size_t ws_size,
                              hipStream_t stream) {
    const float* x    = (const float*)d_in[0];
    const float* W1   = (const float*)d_in[1];
    const float* b1   = (const float*)d_in[2];
    const float* W2   = (const float*)d_in[3];
    const float* b2   = (const float*)d_in[4];
    const float* Wif  = (const float*)d_in[5];
    const float* bif  = (const float*)d_in[6];
    const float* Wout = (const float*)d_in[7];
    const float* Wmem = (const float*)d_in[8];
    float* out = (float*)d_out;

    // ws: weights 601600 | mem fp16 512KB | memT fp16 512KB | fallback link
    char* ws = (char*)d_ws;
    __half2* wp    = (__half2*)ws;
    __half*  memg  = (__half*)(ws + 601600);
    __half*  memTg = (__half*)(ws + 601600 + 524288);
    __half2* linkg = (__half2*)(ws + 601600 + 524288 + 524288);

    convert_weights<<<dim3((WTOT + 255) / 256), dim3(256), 0, stream>>>(W1, W2, Wif, Wout, Wmem, wp);

    hipError_t rc = hipFuncSetAttribute(
        reinterpret_cast<const void*>(&dnc_kernel<true>),
        hipFuncAttributeMaxDynamicSharedMemorySize, SMEM_MAIN);
    if (rc == hipSuccess) {
        dnc_kernel<true><<<dim3(Bb), dim3(1024), SMEM_MAIN, stream>>>(
            x, b1, b2, bif, wp, memg, memTg, linkg, out);
    } else {
        dnc_kernel<false><<<dim3(Bb), dim3(1024), SMEM_FB, stream>>>(
            x, b1, b2, bif, wp, memg, memTg, linkg, out);
    }
}

// Round 13
// 2506.308 us; speedup vs baseline: 1.2381x; 1.2381x over previous
//
#include <hip/hip_runtime.h>
#include <hip/hip_fp16.h>
#include <math.h>

#define Tt 64
#define Bb 16
#define Nn 256
#define Ww 64
#define Rr 4
#define INd 64
#define OUTd 64
#define IFS 471
#define EPSf 1e-6f

// packed half2 weight layout offsets (in half2 units), pairs along K
#define W1OFF   0        // 160*256
#define W2OFF   40960    // 128*256
#define WIFOFF  73728    // 128*471
#define WOUTOFF 134016   // 128*64
#define WMEMOFF 142208   // 128*64
#define WTOT    150400

// link: 256 rows x 129 dwords (258 halfs; 256 used + 2 pad)
#define LROW    129
#define LINKB   (256 * LROW * 4)     // 132096 B
#define SCRB    16384                // bwd partials: 8kc*128p*4 half2 = 16 KB
#define FIXF    3380
#define SMEM_MAIN (LINKB + SCRB + FIXF * 4)   // 162000 <= 163840
#define SMEM_FB   (SCRB + FIXF * 4)

typedef _Float16 h2v __attribute__((ext_vector_type(2)));
__device__ __forceinline__ float fdot2(__half2 a, __half2 b, float c) {
    return __builtin_amdgcn_fdot2(*(h2v*)&a, *(h2v*)&b, c, false);
}
__device__ __forceinline__ __half2 pkh(float a, float b) {
    auto r = __builtin_amdgcn_cvt_pkrtz(a, b);   // __fp16 ext_vector(2)
    return *(__half2*)&r;
}

__device__ __forceinline__ float sigm(float x) { return 1.f / (1.f + expf(-x)); }
__device__ __forceinline__ float oneplus_(float x) {
    return 1.f + fmaxf(x, 0.f) + log1pf(expf(-fabsf(x)));
}
__device__ __forceinline__ float wsum(float v) {
#pragma unroll
    for (int o = 32; o; o >>= 1) v += __shfl_xor(v, o, 64);
    return v;
}
__device__ __forceinline__ float wmaxr(float v) {
#pragma unroll
    for (int o = 32; o; o >>= 1) v = fmaxf(v, __shfl_xor(v, o, 64));
    return v;
}

// shared GEMV-partial body (one icache copy)
__device__ __attribute__((noinline)) float gemv_part(
    const __half2* __restrict__ wP, int stride, int iters,
    const __half2* __restrict__ vin)
{
    float a[8] = {0.f,0.f,0.f,0.f,0.f,0.f,0.f,0.f};
#pragma unroll 1
    for (int j0 = 0; j0 < iters; j0 += 8) {
        __half2 hh[8], vv[8];
#pragma unroll
        for (int u = 0; u < 8; ++u) hh[u] = wP[(j0 + u) * stride];
#pragma unroll
        for (int u = 0; u < 8; ++u) vv[u] = vin[j0 + u];
#pragma unroll
        for (int u = 0; u < 8; ++u) a[u] = fdot2(hh[u], vv[u], a[u]);
    }
    return ((a[0]+a[1])+(a[2]+a[3])) + ((a[4]+a[5])+(a[6]+a[7]));
}

// ---- converter: fp32 weights -> packed half2 (pairs along K) ----
__global__ void convert_weights(const float* __restrict__ W1, const float* __restrict__ W2,
                                const float* __restrict__ Wif, const float* __restrict__ Wout,
                                const float* __restrict__ Wmem, __half2* __restrict__ wp) {
    int i = blockIdx.x * blockDim.x + threadIdx.x;
    if (i >= WTOT) return;
    float a, b;
    if (i < W2OFF)        { int r = i;           int k2 = r >> 8, n = r & 255; a = W1[(2*k2)*256+n];  b = W1[(2*k2+1)*256+n]; }
    else if (i < WIFOFF)  { int t = i - W2OFF;   int k2 = t >> 8, n = t & 255; a = W2[(2*k2)*256+n];  b = W2[(2*k2+1)*256+n]; }
    else if (i < WOUTOFF) { int t = i - WIFOFF;  int k2 = t / IFS, o = t - IFS*k2; a = Wif[(2*k2)*IFS+o]; b = Wif[(2*k2+1)*IFS+o]; }
    else if (i < WMEMOFF) { int t = i - WOUTOFF; int k2 = t >> 6, n = t & 63;  a = Wout[(2*k2)*64+n]; b = Wout[(2*k2+1)*64+n]; }
    else                  { int t = i - WMEMOFF; int k2 = t >> 6, n = t & 63;  a = Wmem[(2*k2)*64+n]; b = Wmem[(2*k2+1)*64+n]; }
    wp[i] = __floats2half2_rn(a, b);
}

template <bool LLINK>
__global__ __launch_bounds__(1024) void dnc_kernel(
    const float* __restrict__ x, const float* __restrict__ b1,
    const float* __restrict__ b2, const float* __restrict__ bif,
    const __half2* __restrict__ wp,
    __half* __restrict__ memg,      // per batch 64*256 halves, [w][n]
    __half2* __restrict__ linkg,    // fallback link
    float* __restrict__ out)
{
    extern __shared__ __align__(16) char smem[];
    const int b = blockIdx.x;
    const int tid = threadIdx.x;
    const int lane = tid & 63;
    const int wv = tid >> 6;

    __half2* l2p = (__half2*)smem;
    __half2* gl2 = linkg + (size_t)b * (256 * LROW);
    float* scr   = (float*)(smem + (LLINK ? LINKB : 0));
    __half* scrh = (__half*)scr;
    float* fx    = (float*)((char*)scr + SCRB);

    // half2 = 4 B = 1 float slot (layout audited).
    // ZONE fx+0..1024: wcdot/wcss (live P4->B9) then fwdh (live B11->P9)
    // fwdh = [q2=2][r=4][n=256] halfs = 2048 halfs = 1024 float slots. FITS.
    float*  s_wcdot = fx + 0;     // 256
    float*  s_wcss  = fx + 256;   // 256
    __half* fwdh    = (__half*)(fx + 0);      // 2048 halfs [q2][r][n]
    __half2* s_ctrlh = (__half2*)(fx + 1024); // 160 h2: [0,32) x, [32,160) rvec
    __half2* s_hh    = (__half2*)(fx + 1184); // 128 h2
    __half2* s_nnh   = (__half2*)(fx + 1312); // 128 h2
    __half2* s_rwh   = (__half2*)(fx + 1440); // 516 h2: [r][129 n-pairs] (pad)
    float* s_z     = fx + 1956;   // 472
    float* s_usage = fx + 2428;   // 256
    float* s_ww    = fx + 2684;   // 256
    float* s_prec  = fx + 2940;   // 256
    float* s_knorm = fx + 3196;   // 4
    float* s_rstr  = fx + 3200;   // 4
    float* s_rmode = fx + 3204;   // 12
    float* s_sc    = fx + 3216;   // 4
    float* s_red   = fx + 3220;   // 32
    float* s_er    = fx + 3252;   // 64
    float* s_wv    = fx + 3316;   // 64  -> FIXF 3380
    float* s_srt   = scr + 1024;  // 256 (mega window only)
    float* s_cp    = scr + 1280;  // 256 (mega window only)

    __half*  memh  = memg + (size_t)b * (Ww * Nn);
    __half2* memh2 = (__half2*)memh;

    auto lread = [&](int idx) -> __half2 {
        if constexpr (LLINK) return l2p[idx]; else return gl2[idx];
    };
    auto lwrite = [&](int idx, __half2 v) {
        if constexpr (LLINK) l2p[idx] = v; else gl2[idx] = v;
    };

    // ---- init (ws/LDS poisoned before every launch) ----
    {
        __half2 z2 = pkh(0.f, 0.f);
#pragma unroll 1
        for (int i = tid; i < 256 * LROW; i += 1024) lwrite(i, z2);
        __half2 e2 = __floats2half2_rn(EPSf, EPSf);
#pragma unroll 1
        for (int j = 0; j < 8; ++j) memh2[tid + j * 1024] = e2;
        if (tid < 516) s_rwh[tid] = z2;
        if (tid < 32) {
            float2 xv = *(const float2*)&x[b * INd + 2 * tid];
            s_ctrlh[tid] = pkh(xv.x, xv.y);
        } else if (tid < 160) s_ctrlh[tid] = z2;
    }
    if (tid < 256) { s_usage[tid] = 0.f; s_ww[tid] = 0.f; s_prec[tid] = 0.f; }

#pragma unroll 1
    for (int t = 0; t < Tt; ++t) {
        __syncthreads();  // B0

        // ---- P1: GEMV1 partials ----
        {
            int kc = wv >> 2, o = (wv & 3) * 64 + lane;
            scr[kc * 256 + o] = gemv_part(wp + W1OFF + kc * 40 * 256 + o, 256, 40,
                                          s_ctrlh + kc * 40);
        }
        __syncthreads();  // B1
        if (tid < 256) {
            float v = tanhf(b1[tid] + ((scr[tid] + scr[256+tid]) + (scr[512+tid] + scr[768+tid])));
            float pv = __shfl_xor(v, 1, 64);
            if ((tid & 1) == 0) s_hh[tid >> 1] = pkh(v, pv);
        }
        __syncthreads();  // B2

        // ---- P2: GEMV2 partials ----
        {
            int kc = wv >> 2, o = (wv & 3) * 64 + lane;
            scr[kc * 256 + o] = gemv_part(wp + W2OFF + kc * 32 * 256 + o, 256, 32,
                                          s_hh + kc * 32);
        }
        __syncthreads();  // B3
        if (tid < 256) {
            float v = tanhf(b2[tid] + ((scr[tid] + scr[256+tid]) + (scr[512+tid] + scr[768+tid])));
            float pv = __shfl_xor(v, 1, 64);
            if ((tid & 1) == 0) s_nnh[tid >> 1] = pkh(v, pv);
        }
        __syncthreads();  // B4

        // ---- P3: GEMV3 partials ----
        {
            int kc = wv >> 3, o = (wv & 7) * 64 + lane;
            if (o < IFS)
                scr[kc * 512 + o] = gemv_part(wp + WIFOFF + kc * 64 * IFS + o, IFS, 64,
                                              s_nnh + kc * 64);
        }
        __syncthreads();  // B5
        if (tid < IFS) s_z[tid] = bif[tid] + scr[tid] + scr[512 + tid];
        __syncthreads();  // B6

        // ---- P4: scalars + usage(+er/wv) + wc dot/ss (merged wave roles) ----
        if (wv < 4) {
            float vz = s_z[lane * 4 + wv];
            float s = wsum(vz * vz);
            if (lane == 0) s_knorm[wv] = sqrtf(s) + EPSf;
        } else if (wv == 4) {
            float vz = s_z[260 + lane];
            float s = wsum(vz * vz);
            if (lane == 0) s_sc[3] = sqrtf(s) + EPSf;
        } else if (wv == 5) {
            if (lane < 4) s_rstr[lane] = oneplus_(s_z[256 + lane]);
            else if (lane >= 8 && lane < 12) {
                int r = lane - 8;
                float a = s_z[459+r], bm = s_z[463+r], c = s_z[467+r];
                float mx = fmaxf(a, fmaxf(bm, c));
                float ea = expf(a-mx), eb = expf(bm-mx), ec = expf(c-mx);
                float inv = 1.f / ((ea+eb)+ec);
                s_rmode[0*4+r] = ea*inv; s_rmode[1*4+r] = eb*inv; s_rmode[2*4+r] = ec*inv;
            } else if (lane == 16) s_sc[0] = oneplus_(s_z[324]);
            else if (lane == 17) s_sc[1] = sigm(s_z[457]);
            else if (lane == 18) s_sc[2] = sigm(s_z[458]);
        } else if (wv >= 8 && wv < 12) {
            int n = tid - 512;
            int np = n >> 1, hi = n & 1;
            float ret = 1.f;
#pragma unroll
            for (int r = 0; r < 4; ++r) {
                float fg = sigm(s_z[453 + r]);
                __half2 rp = s_rwh[r * 129 + np];
                float rwv = hi ? __half2float(__high2half(rp)) : __half2float(__low2half(rp));
                ret *= 1.f - fg * rwv;
            }
            float u = s_usage[n], wwo = s_ww[n];
            s_usage[n] = (u + wwo - u * wwo) * ret;
            if (n < 64) { s_er[n] = sigm(s_z[325 + n]); s_wv[n] = s_z[389 + n]; }
        } else if (wv >= 12) {  // wc content pass on OLD mem (coalesced columns)
            int n = tid - 768;
            float dot = 0.f, ssv = 0.f;
#pragma unroll 1
            for (int w0 = 0; w0 < 64; w0 += 8) {
                __half hv[8];
#pragma unroll
                for (int u = 0; u < 8; ++u) hv[u] = memh[(w0 + u) * 256 + n];
#pragma unroll
                for (int u = 0; u < 8; ++u) {
                    float m = __half2float(hv[u]);
                    ssv = fmaf(m, m, ssv);
                    dot = fmaf(m, s_z[260 + w0 + u], dot);
                }
            }
            s_wcdot[n] = dot; s_wcss[n] = ssv;
        }
        __syncthreads();  // B7

        // ---- P5: rank partials ----
        {
            int q = tid >> 8, n = tid & 255;
            float un = s_usage[n];
            float cnt = 0.f;
            int j0 = q * 64;
#pragma unroll 1
            for (int j = j0; j < j0 + 64; ++j) {
                float uj = s_usage[j];
                if (uj < un || (uj == un && j < n)) cnt += 1.f;
            }
            scr[q * 256 + n] = cnt;
        }
        __syncthreads();  // B8

        // ---- P6: mega (wave 0) ----
        if (wv == 0) {
            int rk[4]; float uu[4];
#pragma unroll
            for (int i = 0; i < 4; ++i) {
                int n = lane * 4 + i;
                float c = scr[n] + scr[256+n] + scr[512+n] + scr[768+n];
                rk[i] = (int)(c + 0.5f);
                uu[i] = s_usage[n];
                s_srt[rk[i]] = uu[i];
            }
            float4 vs = ((const float4*)s_srt)[lane];
            float p1 = vs.x * vs.y, p2 = p1 * vs.z, tot = p2 * vs.w;
            float incl = tot;
#pragma unroll
            for (int off = 1; off < 64; off <<= 1) {
                float tv = __shfl_up(incl, off, 64);
                if (lane >= off) incl *= tv;
            }
            float excl = __shfl_up(incl, 1, 64);
            if (lane == 0) excl = 1.f;
            float4 o4v; o4v.x = excl; o4v.y = excl*vs.x; o4v.z = excl*p1; o4v.w = excl*p2;
            ((float4*)s_cp)[lane] = o4v;

            float sims[4], mx = -1e30f;
#pragma unroll
            for (int i = 0; i < 4; ++i) {
                int n = lane * 4 + i;
                sims[i] = s_wcdot[n] / ((sqrtf(s_wcss[n]) + EPSf) * s_sc[3]) * s_sc[0];
                mx = fmaxf(mx, sims[i]);
            }
            mx = wmaxr(mx);
            float es[4], ls = 0.f;
#pragma unroll
            for (int i = 0; i < 4; ++i) { es[i] = expf(sims[i] - mx); ls += es[i]; }
            ls = wsum(ls);
            float ag = s_sc[1], wg = s_sc[2], inv = 1.f / ls, lw = 0.f;
#pragma unroll
            for (int i = 0; i < 4; ++i) {
                int n = lane * 4 + i;
                float alloc = (1.f - uu[i]) * s_cp[rk[i]];
                float wwn = wg * (ag * alloc + (1.f - ag) * es[i] * inv);
                s_ww[n] = wwn; lw += wwn;
            }
            lw = wsum(lw);
            if (lane == 0) s_red[0] = lw;
        }
        __syncthreads();  // B9

        // ---- P7: link pass, 16-way (kc=8 x p=128, 32 k each) ----
        {
            int kc = tid >> 7, p = tid & 127;
            int c0 = 2 * p, c1 = c0 + 1;
            float wwc0 = s_ww[c0], wwc1 = s_ww[c1];
            float pt0 = s_prec[c0], pt1 = s_prec[c1];
            float acc[8] = {0,0,0,0,0,0,0,0};
            int kbase = kc * 32;
#pragma unroll 1
            for (int k0 = kbase; k0 < kbase + 32; k0 += 8) {
                __half2 lv[8];
#pragma unroll
                for (int u = 0; u < 8; ++u) lv[u] = lread((k0 + u) * LROW + p);
                float l0v[8], l1v[8];
#pragma unroll
                for (int u = 0; u < 8; ++u) {
                    int k = k0 + u;
                    float wk = s_ww[k];
                    float2 lf = __half22float2(lv[u]);
                    float l0 = (1.f - wk - wwc0) * lf.x + wk * pt0;
                    float l1 = (1.f - wk - wwc1) * lf.y + wk * pt1;
                    if (k == c0) l0 = 0.f;
                    if (k == c1) l1 = 0.f;
                    l0v[u] = l0; l1v[u] = l1;
                }
#pragma unroll
                for (int u = 0; u < 8; ++u)
                    lwrite((k0 + u) * LROW + p, pkh(l0v[u], l1v[u]));
                __half2 l0p[4], l1p[4];
#pragma unroll
                for (int i = 0; i < 4; ++i) {
                    l0p[i] = pkh(l0v[2*i], l0v[2*i+1]);
                    l1p[i] = pkh(l1v[2*i], l1v[2*i+1]);
                }
                int kp0 = k0 >> 1;
#pragma unroll
                for (int r = 0; r < 4; ++r) {
                    __half2 rp[4];
#pragma unroll
                    for (int i = 0; i < 4; ++i) rp[i] = s_rwh[r * 129 + kp0 + i];
#pragma unroll
                    for (int i = 0; i < 4; ++i) {
                        acc[r]     = fdot2(l0p[i], rp[i], acc[r]);
                        acc[4 + r] = fdot2(l1p[i], rp[i], acc[4 + r]);
                    }
                }
            }
            __half2* bp = (__half2*)scrh + (kc * 128 + p) * 4;
            bp[0] = pkh(acc[0], acc[1]);
            bp[1] = pkh(acc[2], acc[3]);
            bp[2] = pkh(acc[4], acc[5]);
            bp[3] = pkh(acc[6], acc[7]);
        }
        __syncthreads();  // B10

        // ---- P8: fwd row pass (R11 scheme: q2 halves x r-pairs) + mem RMW + prec ----
        {
            int q2 = tid >> 9, rp2 = (tid >> 8) & 1, n8 = tid & 255;
            int r0 = 2 * rp2, r1 = r0 + 1;
            float f0 = 0.f, f1 = 0.f;
            int base = n8 * LROW + q2 * 64;
#pragma unroll 1
            for (int j0 = 0; j0 < 64; j0 += 8) {
                __half2 lv[8], rA[8], rB[8];
#pragma unroll
                for (int u = 0; u < 8; ++u) lv[u] = lread(base + j0 + u);
#pragma unroll
                for (int u = 0; u < 8; ++u) rA[u] = s_rwh[r0 * 129 + q2 * 64 + j0 + u];
#pragma unroll
                for (int u = 0; u < 8; ++u) rB[u] = s_rwh[r1 * 129 + q2 * 64 + j0 + u];
#pragma unroll
                for (int u = 0; u < 8; ++u) {
                    f0 = fdot2(lv[u], rA[u], f0);
                    f1 = fdot2(lv[u], rB[u], f1);
                }
            }
            fwdh[(q2 * 4 + r0) * 256 + n8] = __float2half(f0);
            fwdh[(q2 * 4 + r1) * 256 + n8] = __float2half(f1);
        }
        {   // mem RMW: 8 half2/thread, coalesced; er/wv wave-uniform broadcast
            __half2 mv[8];
#pragma unroll
            for (int u = 0; u < 8; ++u) mv[u] = memh2[tid + u * 1024];
#pragma unroll
            for (int u = 0; u < 8; ++u) {
                int i2 = tid + u * 1024;
                int w = i2 >> 7, n2 = i2 & 127;
                float er = s_er[w], wvv = s_wv[w];
                float2 mf = __half22float2(mv[u]);
                float wa = s_ww[2*n2], wb = s_ww[2*n2 + 1];
                mf.x = mf.x * (1.f - wa * er) + wa * wvv;
                mf.y = mf.y * (1.f - wb * er) + wb * wvv;
                memh2[i2] = pkh(mf.x, mf.y);
            }
            if (tid < 256) s_prec[tid] = (1.f - s_red[0]) * s_prec[tid] + s_ww[tid];
        }
        __syncthreads();  // B11

        // ---- P9: rc sim (no-max softmax) + bwd/fwd reduce ----
        int rr = tid >> 8, n8c = tid & 255;
        float bwv = 0.f, fwv = 0.f, e_rc = 0.f;
        {
#pragma unroll
            for (int kc = 0; kc < 8; ++kc)
                bwv += __half2float(scrh[(kc * 128 + (n8c >> 1)) * 8 + (n8c & 1) * 4 + rr]);
            fwv = __half2float(fwdh[(0 * 4 + rr) * 256 + n8c])
                + __half2float(fwdh[(1 * 4 + rr) * 256 + n8c]);
            float ssv = 0.f, dv = 0.f;
#pragma unroll 1
            for (int w0 = 0; w0 < 64; w0 += 8) {
                __half hv[8];
#pragma unroll
                for (int u = 0; u < 8; ++u) hv[u] = memh[(w0 + u) * 256 + n8c];
#pragma unroll
                for (int u = 0; u < 8; ++u) {
                    float m = __half2float(hv[u]);
                    ssv = fmaf(m, m, ssv);
                    dv = fmaf(m, s_z[(w0 + u) * 4 + rr], dv);
                }
            }
            float sim = dv / ((sqrtf(ssv) + EPSf) * s_knorm[rr]) * s_rstr[rr];
            e_rc = expf(sim);           // |sim| small: exp safe in fp32 (R11-verified)
            float s = wsum(e_rc);
            if (lane == 0) s_red[wv] = s;
        }
        __syncthreads();  // B12
        {
            float sm = (s_red[rr*4+0] + s_red[rr*4+1]) + (s_red[rr*4+2] + s_red[rr*4+3]);
            float rc = e_rc / sm;
            float v = bwv * s_rmode[0*4+rr] + rc * s_rmode[1*4+rr] + fwv * s_rmode[2*4+rr];
            float pv = __shfl_xor(v, 1, 64);
            if ((n8c & 1) == 0) s_rwh[rr * 129 + (n8c >> 1)] = pkh(v, pv);
        }
        __syncthreads();  // B13

        // ---- P12: rvec partials (half2 + fdot2) ----
        {
            int kc = tid >> 8, o = tid & 255, w = o >> 2, r = o & 3;
            float a = 0.f;
#pragma unroll 1
            for (int j0 = 0; j0 < 32; j0 += 8) {
                __half2 mm[8], rp[8];
#pragma unroll
                for (int u = 0; u < 8; ++u) mm[u] = memh2[w * 128 + kc * 32 + j0 + u];
#pragma unroll
                for (int u = 0; u < 8; ++u) rp[u] = s_rwh[r * 129 + kc * 32 + j0 + u];
#pragma unroll
                for (int u = 0; u < 8; ++u) a = fdot2(mm[u], rp[u], a);
            }
            scr[kc * 256 + o] = a;
        }
        __syncthreads();  // B14

        // ---- P13: rvec reduce -> ctrl pairs + next-x staging ----
        if (tid < 256) {
            float v = (scr[tid] + scr[256+tid]) + (scr[512+tid] + scr[768+tid]);
            float pv = __shfl_xor(v, 1, 64);
            if ((tid & 1) == 0) s_ctrlh[32 + (tid >> 1)] = pkh(v, pv);
        } else if (tid >= 512 && tid < 544) {
            if (t + 1 < Tt) {
                int i = tid - 512;
                float2 xv = *(const float2*)&x[((t + 1) * Bb + b) * INd + 2 * i];
                s_ctrlh[i] = pkh(xv.x, xv.y);
            }
        }
        __syncthreads();  // B15

        // ---- P14: out GEMV partials ----
        {
            int c4 = wv, o4 = lane;
            const __half2* wsrc = (c4 < 8) ? (wp + WOUTOFF + (c4 * 16) * 64 + o4)
                                           : (wp + WMEMOFF + ((c4 - 8) * 16) * 64 + o4);
            const __half2* vsrc = (c4 < 8) ? (s_nnh + c4 * 16)
                                           : (s_ctrlh + 32 + (c4 - 8) * 16);
            scr[c4 * 64 + o4] = gemv_part(wsrc, 64, 16, vsrc);
        }
        __syncthreads();  // B16
        if (tid < 64) {
            float s = 0.f;
#pragma unroll
            for (int g = 0; g < 16; ++g) s += scr[g * 64 + tid];
            out[(t * Bb + b) * OUTd + tid] = s;
        }
        // loop-top barrier covers remaining hazards
    }
}

extern "C" void kernel_launch(void* const* d_in, const int* in_sizes, int n_in,
                              void* d_out, int out_size, void* d_ws, size_t ws_size,
                              hipStream_t stream) {
    const float* x    = (const float*)d_in[0];
    const float* W1   = (const float*)d_in[1];
    const float* b1   = (const float*)d_in[2];
    const float* W2   = (const float*)d_in[3];
    const float* b2   = (const float*)d_in[4];
    const float* Wif  = (const float*)d_in[5];
    const float* bif  = (const float*)d_in[6];
    const float* Wout = (const float*)d_in[7];
    const float* Wmem = (const float*)d_in[8];
    float* out = (float*)d_out;

    // ws: weights 601600 | mem fp16 512KB | fallback link
    char* ws = (char*)d_ws;
    __half2* wp    = (__half2*)ws;
    __half*  memg  = (__half*)(ws + 601600);
    __half2* linkg = (__half2*)(ws + 601600 + 524288);

    convert_weights<<<dim3((WTOT + 255) / 256), dim3(256), 0, stream>>>(W1, W2, Wif, Wout, Wmem, wp);

    hipError_t rc = hipFuncSetAttribute(
        reinterpret_cast<const void*>(&dnc_kernel<true>),
        hipFuncAttributeMaxDynamicSharedMemorySize, SMEM_MAIN);
    if (rc == hipSuccess) {
        dnc_kernel<true><<<dim3(Bb), dim3(1024), SMEM_MAIN, stream>>>(
            x, b1, b2, bif, wp, memg, linkg, out);
    } else {
        dnc_kernel<false><<<dim3(Bb), dim3(1024), SMEM_FB, stream>>>(
            x, b1, b2, bif, wp, memg, linkg, out);
    }
}

// Round 14
// 2300.096 us; speedup vs baseline: 1.3491x; 1.0897x over previous
//
#include <hip/hip_runtime.h>
#include <hip/hip_fp16.h>
#include <math.h>

#define Tt 64
#define Bb 16
#define Nn 256
#define Ww 64
#define Rr 4
#define INd 64
#define OUTd 64
#define IFS 471
#define EPSf 1e-6f

// packed half2 weight layout offsets (in half2 units), pairs along K
#define W1OFF   0        // 160*256
#define W2OFF   40960    // 128*256
#define WIFOFF  73728    // 128*471
#define WOUTOFF 134016   // 128*64
#define WMEMOFF 142208   // 128*64
#define WTOT    150400

// link: 256 rows x 129 dwords (258 halfs; 256 used + 2 pad)
#define LROW    129
#define LINKB   (256 * LROW * 4)     // 132096 B
#define SCRB    16384                // 4096 floats / 8192 halfs
#define FIXF    3760
#define SMEM_MAIN (LINKB + SCRB + FIXF * 4)   // 163520 <= 163840
#define SMEM_FB   (SCRB + FIXF * 4)

typedef _Float16 h2v __attribute__((ext_vector_type(2)));
__device__ __forceinline__ float fdot2(__half2 a, __half2 b, float c) {
    return __builtin_amdgcn_fdot2(*(h2v*)&a, *(h2v*)&b, c, false);
}
__device__ __forceinline__ __half2 pkh(float a, float b) {
    auto r = __builtin_amdgcn_cvt_pkrtz(a, b);   // __fp16 ext_vector(2)
    return *(__half2*)&r;
}

__device__ __forceinline__ float sigm(float x) { return 1.f / (1.f + expf(-x)); }
__device__ __forceinline__ float oneplus_(float x) {
    return 1.f + fmaxf(x, 0.f) + log1pf(expf(-fabsf(x)));
}
__device__ __forceinline__ float wsum(float v) {
#pragma unroll
    for (int o = 32; o; o >>= 1) v += __shfl_xor(v, o, 64);
    return v;
}
__device__ __forceinline__ float wmaxr(float v) {
#pragma unroll
    for (int o = 32; o; o >>= 1) v = fmaxf(v, __shfl_xor(v, o, 64));
    return v;
}

// shared GEMV-partial body: half2 weight column (runtime stride) dot half2
// vector in LDS via v_dot2_f32_f16. noinline -> one icache copy.
__device__ __attribute__((noinline)) float gemv_part(
    const __half2* __restrict__ wP, int stride, int iters,
    const __half2* __restrict__ vin)
{
    float a[8] = {0.f,0.f,0.f,0.f,0.f,0.f,0.f,0.f};
#pragma unroll 1
    for (int j0 = 0; j0 < iters; j0 += 8) {
        __half2 hh[8], vv[8];
#pragma unroll
        for (int u = 0; u < 8; ++u) hh[u] = wP[(j0 + u) * stride];
#pragma unroll
        for (int u = 0; u < 8; ++u) vv[u] = vin[j0 + u];
#pragma unroll
        for (int u = 0; u < 8; ++u) a[u] = fdot2(hh[u], vv[u], a[u]);
    }
    return ((a[0]+a[1])+(a[2]+a[3])) + ((a[4]+a[5])+(a[6]+a[7]));
}

// ---- converter: fp32 weights -> packed half2 (pairs along K) ----
__global__ void convert_weights(const float* __restrict__ W1, const float* __restrict__ W2,
                                const float* __restrict__ Wif, const float* __restrict__ Wout,
                                const float* __restrict__ Wmem, __half2* __restrict__ wp) {
    int i = blockIdx.x * blockDim.x + threadIdx.x;
    if (i >= WTOT) return;
    float a, b;
    if (i < W2OFF)        { int r = i;           int k2 = r >> 8, n = r & 255; a = W1[(2*k2)*256+n];  b = W1[(2*k2+1)*256+n]; }
    else if (i < WIFOFF)  { int t = i - W2OFF;   int k2 = t >> 8, n = t & 255; a = W2[(2*k2)*256+n];  b = W2[(2*k2+1)*256+n]; }
    else if (i < WOUTOFF) { int t = i - WIFOFF;  int k2 = t / IFS, o = t - IFS*k2; a = Wif[(2*k2)*IFS+o]; b = Wif[(2*k2+1)*IFS+o]; }
    else if (i < WMEMOFF) { int t = i - WOUTOFF; int k2 = t >> 6, n = t & 63;  a = Wout[(2*k2)*64+n]; b = Wout[(2*k2+1)*64+n]; }
    else                  { int t = i - WMEMOFF; int k2 = t >> 6, n = t & 63;  a = Wmem[(2*k2)*64+n]; b = Wmem[(2*k2+1)*64+n]; }
    wp[i] = __floats2half2_rn(a, b);
}

template <bool LLINK>
__global__ __launch_bounds__(1024) void dnc_kernel(
    const float* __restrict__ x, const float* __restrict__ b1,
    const float* __restrict__ b2, const float* __restrict__ bif,
    const __half2* __restrict__ wp,
    __half* __restrict__ memg,      // per batch 64*256 halves, [w][n]
    __half2* __restrict__ linkg,    // fallback link
    float* __restrict__ out)
{
    extern __shared__ __align__(16) char smem[];
    const int b = blockIdx.x;
    const int tid = threadIdx.x;
    const int lane = tid & 63;
    const int wv = tid >> 6;

    __half2* l2p = (__half2*)smem;
    __half2* gl2 = linkg + (size_t)b * (256 * LROW);
    float* scr   = (float*)(smem + (LLINK ? LINKB : 0));
    __half* scrh = (__half*)scr;
    float* fx    = (float*)((char*)scr + SCRB);

    float*   s_rw    = fx + 0;                    // 1024 [n][r] fp32
    __half2* s_ctrlh = (__half2*)(fx + 1024);     // 160: [0,32) x pairs, [32,160) rvec pairs
    __half2* s_hh    = (__half2*)(fx + 1184);     // 128
    __half2* s_nnh   = (__half2*)(fx + 1312);     // 128
    __half2* s_rwh   = (__half2*)(fx + 1440);     // 512 [r][128 n-pairs]
    float* s_z     = fx + 1952;   // 472
    float* s_usage = fx + 2424;   // 256
    float* s_ww    = fx + 2680;   // 256
    float* s_prec  = fx + 2936;   // 256
    float* s_wcdot = fx + 3192;   // 256
    float* s_wcss  = fx + 3448;   // 256
    float* s_knorm = fx + 3704;   // 4
    float* s_rstr  = fx + 3708;   // 4
    float* s_rmode = fx + 3712;   // 12
    float* s_sc    = fx + 3724;   // 4
    float* s_red   = fx + 3728;   // 32
    float* s_srt   = scr + 1024;  // 256 (mega only)
    float* s_cp    = scr + 1280;  // 256 (mega only)

    __half*  memh  = memg + (size_t)b * (Ww * Nn);
    __half2* memh2 = (__half2*)memh;

    auto lread = [&](int idx) -> __half2 {
        if constexpr (LLINK) return l2p[idx]; else return gl2[idx];
    };
    auto lwrite = [&](int idx, __half2 v) {
        if constexpr (LLINK) l2p[idx] = v; else gl2[idx] = v;
    };

    // ---- init (ws/LDS poisoned before every launch) ----
    {
        __half2 z2 = pkh(0.f, 0.f);
#pragma unroll 1
        for (int i = tid; i < 256 * LROW; i += 1024) lwrite(i, z2);
        __half2 e2 = __floats2half2_rn(EPSf, EPSf);
#pragma unroll 1
        for (int j = 0; j < 8; ++j) memh2[tid + j * 1024] = e2;
        if (tid < 512) s_rwh[tid] = z2;
        if (tid < 32) {
            float2 xv = *(const float2*)&x[b * INd + 2 * tid];
            s_ctrlh[tid] = pkh(xv.x, xv.y);
        } else if (tid < 160) s_ctrlh[tid] = z2;
    }
    if (tid < 256) {
        s_usage[tid] = 0.f; s_ww[tid] = 0.f; s_prec[tid] = 0.f;
        s_rw[tid*4+0] = 0.f; s_rw[tid*4+1] = 0.f; s_rw[tid*4+2] = 0.f; s_rw[tid*4+3] = 0.f;
    }

#pragma unroll 1
    for (int t = 0; t < Tt; ++t) {
        __syncthreads();  // B0

        // ---- P1: GEMV1 partials ----
        {
            int kc = wv >> 2, o = (wv & 3) * 64 + lane;
            scr[kc * 256 + o] = gemv_part(wp + W1OFF + kc * 40 * 256 + o, 256, 40,
                                          s_ctrlh + kc * 40);
        }
        __syncthreads();  // B1
        if (tid < 256) {
            float v = tanhf(b1[tid] + ((scr[tid] + scr[256+tid]) + (scr[512+tid] + scr[768+tid])));
            float pv = __shfl_xor(v, 1, 64);
            if ((tid & 1) == 0) s_hh[tid >> 1] = pkh(v, pv);
        }
        __syncthreads();  // B2

        // ---- P2: GEMV2 partials ----
        {
            int kc = wv >> 2, o = (wv & 3) * 64 + lane;
            scr[kc * 256 + o] = gemv_part(wp + W2OFF + kc * 32 * 256 + o, 256, 32,
                                          s_hh + kc * 32);
        }
        __syncthreads();  // B3
        if (tid < 256) {
            float v = tanhf(b2[tid] + ((scr[tid] + scr[256+tid]) + (scr[512+tid] + scr[768+tid])));
            float pv = __shfl_xor(v, 1, 64);
            if ((tid & 1) == 0) s_nnh[tid >> 1] = pkh(v, pv);
        }
        __syncthreads();  // B4

        // ---- P3: GEMV3 partials ----
        {
            int kc = wv >> 3, o = (wv & 7) * 64 + lane;
            if (o < IFS)
                scr[kc * 512 + o] = gemv_part(wp + WIFOFF + kc * 64 * IFS + o, IFS, 64,
                                              s_nnh + kc * 64);
        }
        __syncthreads();  // B5
        if (tid < IFS) s_z[tid] = bif[tid] + scr[tid] + scr[512 + tid];
        __syncthreads();  // B6

        // ---- P4: scalars + usage + wc dot/ss (merged wave roles) ----
        if (wv < 4) {
            float vz = s_z[lane * 4 + wv];
            float s = wsum(vz * vz);
            if (lane == 0) s_knorm[wv] = sqrtf(s) + EPSf;
        } else if (wv == 4) {
            float vz = s_z[260 + lane];
            float s = wsum(vz * vz);
            if (lane == 0) s_sc[3] = sqrtf(s) + EPSf;
        } else if (wv == 5) {
            if (lane < 4) s_rstr[lane] = oneplus_(s_z[256 + lane]);
            else if (lane >= 8 && lane < 12) {
                int r = lane - 8;
                float a = s_z[459+r], bm = s_z[463+r], c = s_z[467+r];
                float mx = fmaxf(a, fmaxf(bm, c));
                float ea = expf(a-mx), eb = expf(bm-mx), ec = expf(c-mx);
                float inv = 1.f / ((ea+eb)+ec);
                s_rmode[0*4+r] = ea*inv; s_rmode[1*4+r] = eb*inv; s_rmode[2*4+r] = ec*inv;
            } else if (lane == 16) s_sc[0] = oneplus_(s_z[324]);
            else if (lane == 17) s_sc[1] = sigm(s_z[457]);
            else if (lane == 18) s_sc[2] = sigm(s_z[458]);
        } else if (wv >= 8 && wv < 12) {
            int n = tid - 512;
            float ret = 1.f;
#pragma unroll
            for (int r = 0; r < 4; ++r) {
                float fg = sigm(s_z[453 + r]);
                ret *= 1.f - fg * s_rw[n*4 + r];
            }
            float u = s_usage[n], wwo = s_ww[n];
            s_usage[n] = (u + wwo - u * wwo) * ret;
        } else if (wv >= 12) {
            int n = tid - 768;
            float dot = 0.f, ssv = 0.f;
#pragma unroll 1
            for (int w0 = 0; w0 < 64; w0 += 8) {
                __half hv[8];
#pragma unroll
                for (int u = 0; u < 8; ++u) hv[u] = memh[(w0 + u) * 256 + n];
#pragma unroll
                for (int u = 0; u < 8; ++u) {
                    float m = __half2float(hv[u]);
                    ssv = fmaf(m, m, ssv);
                    dot = fmaf(m, s_z[260 + w0 + u], dot);
                }
            }
            s_wcdot[n] = dot; s_wcss[n] = ssv;
        }
        __syncthreads();  // B7

        // ---- P5: rank partials ----
        {
            int q = tid >> 8, n = tid & 255;
            float un = s_usage[n];
            float cnt = 0.f;
            int j0 = q * 64;
#pragma unroll 1
            for (int j = j0; j < j0 + 64; ++j) {
                float uj = s_usage[j];
                if (uj < un || (uj == un && j < n)) cnt += 1.f;
            }
            scr[q * 256 + n] = cnt;
        }
        __syncthreads();  // B8

        // ---- P6: mega (wave 0) ----
        if (wv == 0) {
            int rk[4]; float uu[4];
#pragma unroll
            for (int i = 0; i < 4; ++i) {
                int n = lane * 4 + i;
                float c = scr[n] + scr[256+n] + scr[512+n] + scr[768+n];
                rk[i] = (int)(c + 0.5f);
                uu[i] = s_usage[n];
                s_srt[rk[i]] = uu[i];
            }
            float4 vs = ((const float4*)s_srt)[lane];
            float p1 = vs.x * vs.y, p2 = p1 * vs.z, tot = p2 * vs.w;
            float incl = tot;
#pragma unroll
            for (int off = 1; off < 64; off <<= 1) {
                float tv = __shfl_up(incl, off, 64);
                if (lane >= off) incl *= tv;
            }
            float excl = __shfl_up(incl, 1, 64);
            if (lane == 0) excl = 1.f;
            float4 o4v; o4v.x = excl; o4v.y = excl*vs.x; o4v.z = excl*p1; o4v.w = excl*p2;
            ((float4*)s_cp)[lane] = o4v;

            float sims[4], mx = -1e30f;
#pragma unroll
            for (int i = 0; i < 4; ++i) {
                int n = lane * 4 + i;
                sims[i] = s_wcdot[n] / ((sqrtf(s_wcss[n]) + EPSf) * s_sc[3]) * s_sc[0];
                mx = fmaxf(mx, sims[i]);
            }
            mx = wmaxr(mx);
            float es[4], ls = 0.f;
#pragma unroll
            for (int i = 0; i < 4; ++i) { es[i] = expf(sims[i] - mx); ls += es[i]; }
            ls = wsum(ls);
            float ag = s_sc[1], wg = s_sc[2], inv = 1.f / ls, lw = 0.f;
#pragma unroll
            for (int i = 0; i < 4; ++i) {
                int n = lane * 4 + i;
                float alloc = (1.f - uu[i]) * s_cp[rk[i]];
                float wwn = wg * (ag * alloc + (1.f - ag) * es[i] * inv);
                s_ww[n] = wwn; lw += wwn;
            }
            lw = wsum(lw);
            if (lane == 0) s_red[0] = lw;
        }
        __syncthreads();  // B9

        // ---- P7: link col pass (8 waves; bwd via fdot2) || mem RMW (8 waves) ----
        if (tid < 512) {
            int kc = tid >> 7, p = tid & 127;
            int c0 = 2 * p, c1 = c0 + 1;
            float wwc0 = s_ww[c0], wwc1 = s_ww[c1];
            float pt0 = s_prec[c0], pt1 = s_prec[c1];
            float acc[8] = {0,0,0,0,0,0,0,0};
            int kbase = kc * 64;
#pragma unroll 1
            for (int k0 = kbase; k0 < kbase + 64; k0 += 8) {
                __half2 lv[8];
#pragma unroll
                for (int u = 0; u < 8; ++u) lv[u] = lread((k0 + u) * LROW + p);
                float l0v[8], l1v[8];
#pragma unroll
                for (int u = 0; u < 8; ++u) {
                    int k = k0 + u;
                    float wk = s_ww[k];
                    float2 lf = __half22float2(lv[u]);
                    float l0 = (1.f - wk - wwc0) * lf.x + wk * pt0;
                    float l1 = (1.f - wk - wwc1) * lf.y + wk * pt1;
                    if (k == c0) l0 = 0.f;
                    if (k == c1) l1 = 0.f;
                    l0v[u] = l0; l1v[u] = l1;
                }
#pragma unroll
                for (int u = 0; u < 8; ++u)
                    lwrite((k0 + u) * LROW + p, pkh(l0v[u], l1v[u]));
                __half2 l0p[4], l1p[4];
#pragma unroll
                for (int i = 0; i < 4; ++i) {
                    l0p[i] = pkh(l0v[2*i], l0v[2*i+1]);
                    l1p[i] = pkh(l1v[2*i], l1v[2*i+1]);
                }
                int kp0 = k0 >> 1;
#pragma unroll
                for (int r = 0; r < 4; ++r) {
                    __half2 rp[4];
#pragma unroll
                    for (int i = 0; i < 4; ++i) rp[i] = s_rwh[r * 128 + kp0 + i];
#pragma unroll
                    for (int i = 0; i < 4; ++i) {
                        acc[r]     = fdot2(l0p[i], rp[i], acc[r]);
                        acc[4 + r] = fdot2(l1p[i], rp[i], acc[4 + r]);
                    }
                }
            }
            __half2* bp = (__half2*)scrh + (kc * 128 + p) * 4;
            bp[0] = pkh(acc[0], acc[1]);
            bp[1] = pkh(acc[2], acc[3]);
            bp[2] = pkh(acc[4], acc[5]);
            bp[3] = pkh(acc[6], acc[7]);
        } else {
            int t0 = tid - 512;
#pragma unroll 1
            for (int jb = 0; jb < 2; ++jb) {
                __half2 mv[8];
#pragma unroll
                for (int j = 0; j < 8; ++j) mv[j] = memh2[t0 + (jb * 8 + j) * 512];
#pragma unroll
                for (int j = 0; j < 8; ++j) {
                    int i2 = t0 + (jb * 8 + j) * 512;
                    int w = i2 >> 7, n2 = i2 & 127;
                    float er = sigm(s_z[325 + w]);
                    float wvv = s_z[389 + w];
                    float2 mf = __half22float2(mv[j]);
                    float wa = s_ww[2*n2], wb = s_ww[2*n2 + 1];
                    mf.x = mf.x * (1.f - wa * er) + wa * wvv;
                    mf.y = mf.y * (1.f - wb * er) + wb * wvv;
                    memh2[i2] = __floats2half2_rn(mf.x, mf.y);
                }
            }
        }
        __syncthreads();  // B10

        // ---- P8: fwd row pass (fdot2, no unpack) + prec update ----
        {
            int q = tid >> 8, n8 = tid & 255;
            float f[4] = {0.f, 0.f, 0.f, 0.f};
            int base = n8 * LROW + q * 32;
#pragma unroll 1
            for (int j0 = 0; j0 < 32; j0 += 8) {
                __half2 lv[8];
#pragma unroll
                for (int u = 0; u < 8; ++u) lv[u] = lread(base + j0 + u);
#pragma unroll
                for (int r = 0; r < 4; ++r) {
                    __half2 rp[8];
#pragma unroll
                    for (int u = 0; u < 8; ++u) rp[u] = s_rwh[r * 128 + q * 32 + j0 + u];
#pragma unroll
                    for (int u = 0; u < 8; ++u) f[r] = fdot2(lv[u], rp[u], f[r]);
                }
            }
            __half2* fp2 = (__half2*)(scrh + 4096) + (q * 256 + n8) * 2;
            fp2[0] = pkh(f[0], f[1]);
            fp2[1] = pkh(f[2], f[3]);
            if (q == 0) s_prec[n8] = (1.f - s_red[0]) * s_prec[n8] + s_ww[n8];
        }
        __syncthreads();  // B11

        // ---- P9: rc sim + bwd/fwd reduce (no-max softmax: one reduce round) ----
        int rr = tid >> 8, n8c = tid & 255;
        float bwv = 0.f, fwv = 0.f, e_rc = 0.f;
        {
#pragma unroll
            for (int kc = 0; kc < 4; ++kc)
                bwv += __half2float(scrh[(kc * 128 + (n8c >> 1)) * 8 + (n8c & 1) * 4 + rr]);
#pragma unroll
            for (int qq = 0; qq < 4; ++qq)
                fwv += __half2float(scrh[4096 + (qq * 256 + n8c) * 4 + rr]);
            float ssv = 0.f, dv = 0.f;
#pragma unroll 1
            for (int w0 = 0; w0 < 64; w0 += 8) {
                __half hv[8];
#pragma unroll
                for (int u = 0; u < 8; ++u) hv[u] = memh[(w0 + u) * 256 + n8c];
#pragma unroll
                for (int u = 0; u < 8; ++u) {
                    float m = __half2float(hv[u]);
                    ssv = fmaf(m, m, ssv);
                    dv = fmaf(m, s_z[(w0 + u) * 4 + rr], dv);
                }
            }
            float sim = dv / ((sqrtf(ssv) + EPSf) * s_knorm[rr]) * s_rstr[rr];
            e_rc = expf(sim);        // |sim| small (strength-scaled cosine); R11/R13-verified
            float s = wsum(e_rc);
            if (lane == 0) s_red[16 + wv] = s;
        }
        __syncthreads();  // B12
        {
            float sm = (s_red[16+rr*4+0] + s_red[16+rr*4+1]) + (s_red[16+rr*4+2] + s_red[16+rr*4+3]);
            float rc = e_rc / sm;
            float v = bwv * s_rmode[0*4+rr] + rc * s_rmode[1*4+rr] + fwv * s_rmode[2*4+rr];
            s_rw[n8c*4 + rr] = v;
            float pv = __shfl_xor(v, 1, 64);
            if ((n8c & 1) == 0) s_rwh[rr * 128 + (n8c >> 1)] = pkh(v, pv);
        }
        __syncthreads();  // B13

        // ---- P12: rvec partials ----
        {
            int kc = tid >> 8, o = tid & 255, w = o >> 2, r = o & 3;
            const __half* mw = memh + w * 256 + kc * 64;
            float a = 0.f;
#pragma unroll 1
            for (int j0 = 0; j0 < 64; j0 += 8) {
                __half hv[8];
#pragma unroll
                for (int u = 0; u < 8; ++u) hv[u] = mw[j0 + u];
#pragma unroll
                for (int u = 0; u < 8; ++u)
                    a = fmaf(__half2float(hv[u]), s_rw[(kc * 64 + j0 + u) * 4 + r], a);
            }
            scr[kc * 256 + o] = a;
        }
        __syncthreads();  // B14

        // ---- P13: rvec reduce -> ctrl pairs + next-x staging ----
        if (tid < 256) {
            float v = (scr[tid] + scr[256+tid]) + (scr[512+tid] + scr[768+tid]);
            float pv = __shfl_xor(v, 1, 64);
            if ((tid & 1) == 0) s_ctrlh[32 + (tid >> 1)] = pkh(v, pv);
        } else if (tid >= 512 && tid < 544) {
            if (t + 1 < Tt) {
                int i = tid - 512;
                float2 xv = *(const float2*)&x[((t + 1) * Bb + b) * INd + 2 * i];
                s_ctrlh[i] = pkh(xv.x, xv.y);
            }
        }
        __syncthreads();  // B15

        // ---- P14: out GEMV partials (shared gemv_part; rvec read from ctrl pairs) ----
        {
            int c4 = wv, o4 = lane;
            const __half2* wsrc = (c4 < 8) ? (wp + WOUTOFF + (c4 * 16) * 64 + o4)
                                           : (wp + WMEMOFF + ((c4 - 8) * 16) * 64 + o4);
            const __half2* vsrc = (c4 < 8) ? (s_nnh + c4 * 16)
                                           : (s_ctrlh + 32 + (c4 - 8) * 16);
            scr[c4 * 64 + o4] = gemv_part(wsrc, 64, 16, vsrc);
        }
        __syncthreads();  // B16
        if (tid < 64) {
            float s = 0.f;
#pragma unroll
            for (int g = 0; g < 16; ++g) s += scr[g * 64 + tid];
            out[(t * Bb + b) * OUTd + tid] = s;
        }
        // loop-top barrier covers remaining hazards
    }
}

extern "C" void kernel_launch(void* const* d_in, const int* in_sizes, int n_in,
                              void* d_out, int out_size, void* d_ws, size_t ws_size,
                              hipStream_t stream) {
    const float* x    = (const float*)d_in[0];
    const float* W1   = (const float*)d_in[1];
    const float* b1   = (const float*)d_in[2];
    const float* W2   = (const float*)d_in[3];
    const float* b2   = (const float*)d_in[4];
    const float* Wif  = (const float*)d_in[5];
    const float* bif  = (const float*)d_in[6];
    const float* Wout = (const float*)d_in[7];
    const float* Wmem = (const float*)d_in[8];
    float* out = (float*)d_out;

    // ws: [0, 601600) packed half2 weights; [601600, +512KB) mem fp16; then fallback link.
    char* ws = (char*)d_ws;
    __half2* wp    = (__half2*)ws;
    __half*  memg  = (__half*)(ws + 601600);
    __half2* linkg = (__half2*)(ws + 601600 + 524288);

    convert_weights<<<dim3((WTOT + 255) / 256), dim3(256), 0, stream>>>(W1, W2, Wif, Wout, Wmem, wp);

    hipError_t rc = hipFuncSetAttribute(
        reinterpret_cast<const void*>(&dnc_kernel<true>),
        hipFuncAttributeMaxDynamicSharedMemorySize, SMEM_MAIN);
    if (rc == hipSuccess) {
        dnc_kernel<true><<<dim3(Bb), dim3(1024), SMEM_MAIN, stream>>>(
            x, b1, b2, bif, wp, memg, linkg, out);
    } else {
        dnc_kernel<false><<<dim3(Bb), dim3(1024), SMEM_FB, stream>>>(
            x, b1, b2, bif, wp, memg, linkg, out);
    }
}